// Round 7
// baseline (746.200 us; speedup 1.0000x reference)
//
#include <hip/hip_runtime.h>
#include <math.h>

// Problem constants (from reference)
#define Bn    256
#define Tn    1024
#define In    64
#define Pn    256
#define En    128
#define NOUTn 64
#define LN_EPS 1e-5f

// softmax factorization constants (TEMP=8):
// z_j ∝ exp((j-2)*frac/4) * exp(-(j-2)^2/8)  (common exp(-frac^2/8) cancels)
#define C1f 0.3606737602222409f     // log2(e)/4
#define K1f 0.8824969025845955f     // exp(-1/8)
#define K2f 0.6065306597126334f     // exp(-4/8)

typedef float f32x2 __attribute__((ext_vector_type(2)));

__device__ __forceinline__ float tanh_fast(float x) {
    float e = __builtin_amdgcn_exp2f(x * 2.88539008177793f);   // e^(2x)
    return 1.0f - 2.0f * __builtin_amdgcn_rcpf(e + 1.0f);
}
__device__ __forceinline__ f32x2 tanh2(f32x2 x) {
    f32x2 e;
    e[0] = __builtin_amdgcn_exp2f(x[0] * 2.88539008177793f);
    e[1] = __builtin_amdgcn_exp2f(x[1] * 2.88539008177793f);
    f32x2 r;
    r[0] = __builtin_amdgcn_rcpf(e[0] + 1.0f);
    r[1] = __builtin_amdgcn_rcpf(e[1] + 1.0f);
    return 1.0f - 2.0f * r;
}

template<int CTRL, int RMASK>
__device__ __forceinline__ float dpp_add(float x) {
    return x + __int_as_float(__builtin_amdgcn_update_dpp(
        0, __float_as_int(x), CTRL, RMASK, 0xF, false));
}
__device__ __forceinline__ void wave_sum64_x3(float& x, float& y, float& z) {
#define LVL(C, R) x = dpp_add<C, R>(x); y = dpp_add<C, R>(y); z = dpp_add<C, R>(z);
    LVL(0x111, 0xF)
    LVL(0x112, 0xF)
    LVL(0x114, 0xF)
    LVL(0x118, 0xF)
    LVL(0x142, 0xA)
    LVL(0x143, 0xC)
#undef LVL
    x = __int_as_float(__builtin_amdgcn_readlane(__float_as_int(x), 63));
    y = __int_as_float(__builtin_amdgcn_readlane(__float_as_int(y), 63));
    z = __int_as_float(__builtin_amdgcn_readlane(__float_as_int(z), 63));
}

// ===========================================================================
// FUSED kernel: 256 blocks x 192 threads (3 waves), one block per batch.
//   wave0 (consumer): the scan4 step (best measured: 367us) over 16 chunks
//                     of 64 timesteps, emb read from ws global w/ prefetch.
//   waves1-2 (producers): emb for THIS batch, chunk k+2 while consumer scans
//                     chunk k. wave1: e=0..63, wave2: e=64..127; W row in
//                     VGPRs; x rows broadcast-loaded (threadIdx-derived addr
//                     -> stays VMEM, avoids the R3 s_load serialization).
// One __syncthreads per chunk (producers sleep at the barrier ~75% of the
// time; 3 waves sit on 3 different SIMDs -> no issue contention).
// Producer math is bit-identical to R4/R5's embgemm (same order, tanh_fast).
// ===========================================================================
#define LDSF_FLOATS (Pn * En + Pn)
#define LDSF_BYTES  (LDSF_FLOATS * 4)

__global__ __launch_bounds__(192, 1)
void fused_kernel(const float* __restrict__ x,
                  const float* __restrict__ pointer_init,
                  const float* __restrict__ W_in, const float* __restrict__ b_in,
                  const float* __restrict__ ln_w, const float* __restrict__ ln_b,
                  const float* __restrict__ jump_dest,
                  const float* __restrict__ Wg,  const float* __restrict__ bg,
                  const float* __restrict__ cs_ptr,
                  const float* __restrict__ Wo,  const float* __restrict__ bo,
                  float* __restrict__ emb4, float* __restrict__ out) {
    extern __shared__ float lds[];
    float* mem = lds;              // ring: [row][2*l + c], channel pair per lane
    float* jd  = lds + Pn * En;    // jump_dest copy

    const int b   = blockIdx.x;
    const int tid = threadIdx.x;

    if (tid >= 64) {
        // ================= PRODUCERS (waves 1,2) =================
        const int e = tid - 64;            // 0..127
        float w[In];
        {
            const float4* w4 = (const float4*)(W_in + e * In);
            #pragma unroll
            for (int i = 0; i < 16; ++i) {
                float4 v = w4[i];
                w[4*i] = v.x; w[4*i+1] = v.y; w[4*i+2] = v.z; w[4*i+3] = v.w;
            }
        }
        const float be = b_in[e];
        const float* xb  = x + (size_t)b * Tn * In;
        float*       dst = emb4 + ((size_t)b << 17);

#define PRODUCE(K) {                                                     \
    for (int tt = 0; tt < 64; ++tt) {                                    \
        const int t = (K) * 64 + tt;                                     \
        const float4* xr = (const float4*)(xb + t * In);                 \
        float a0 = 0.f, a1 = 0.f, a2 = 0.f, a3 = 0.f;                    \
        _Pragma("unroll")                                                \
        for (int i = 0; i < 16; ++i) {                                   \
            float4 xv = xr[i];                                           \
            a0 += xv.x * w[4*i];   a1 += xv.y * w[4*i+1];                \
            a2 += xv.z * w[4*i+2]; a3 += xv.w * w[4*i+3];                \
        }                                                                \
        dst[((t >> 2) * 128 + e) * 4 + (t & 3)] =                        \
            tanh_fast((a0 + a1) + (a2 + a3) + be);                       \
    }                                                                    \
}
        PRODUCE(0)
        PRODUCE(1)
        __syncthreads();                   // #1: chunks 0,1 ready
        for (int k = 0; k < 16; ++k) {
            if (k + 2 < 16) PRODUCE(k + 2)
            __syncthreads();               // chunk boundary
        }
#undef PRODUCE
        __syncthreads();                   // final: hid broadcast
        return;
    }

    // ================= CONSUMER (wave 0): scan4 step, chunked =================
    const int l = tid;

    float4* m4 = (float4*)mem;
    for (int i = l; i < Pn * En / 4; i += 64) m4[i] = make_float4(0.f, 0.f, 0.f, 0.f);
    for (int i = l; i < Pn; i += 64) jd[i] = jump_dest[i];

    const f32x2 lnw = {ln_w[l], ln_w[l + 64]};
    const f32x2 lnb = {ln_b[l], ln_b[l + 64]};
    const f32x2 wg  = {Wg[l],   Wg[l + 64]};
    const float bgs = bg[0];
    const float cs  = 1.0f / (1.0f + expf(-cs_ptr[0]));
    f32x2 hid = {0.f, 0.f};

    float* myb = mem + 2 * l;

    // ---- pipeline state (scan4: forced jump to pointer_init at t=0) ----
    float jl      = 1.0f;
    float jt_cur  = pointer_init[b];
    float ptrW    = 0.f;
    int   baseW   = 0;
    float jtW_pre = 0.f;
    float z0 = 0.f, z1 = 0.f, z2 = 1.f, z3 = 0.f, z4 = 0.f, inv = 1.f;
    f32x2 wnb0 = {0,0}, wnb1 = {0,0}, wnb2 = {0,0}, wnb3 = {0,0}, wnb4 = {0,0};
    float *wp0 = myb, *wp1 = myb, *wp2 = myb, *wp3 = myb, *wp4 = myb;

    __syncthreads();                       // #1: emb chunks 0,1 ready

    const float4* e40 = (const float4*)(emb4 + ((size_t)b << 17)) + l;   // ch l
    const float4* e41 = e40 + 64;                                        // ch l+64
    float4 A0 = e40[0],   A1 = e41[0];
    float4 B0 = e40[128], B1 = e41[128];

#define SSTEP(EC0, EC1) {                                                      \
    float ptr; int base;                                                       \
    f32x2 nb0, nb1, nb2, nb3, nb4;                                             \
    float *p0, *p1, *p2, *p3, *p4;                                             \
    float jt_nxt;                                                              \
    if (__builtin_amdgcn_readfirstlane(__float_as_int(jl)) > 0) {              \
        /* JUMP: full gather + weight recompute */                             \
        ptr  = jt_cur;                                                         \
        base = (int)ptr; base = base > 255 ? 255 : base;                       \
        p0 = mem + (((base + 254) & 255) << 7) + 2 * l;                        \
        p1 = mem + (((base + 255) & 255) << 7) + 2 * l;                        \
        p2 = mem + (base << 7) + 2 * l;                                        \
        p3 = mem + (((base + 1) & 255) << 7) + 2 * l;                          \
        p4 = mem + (((base + 2) & 255) << 7) + 2 * l;                          \
        nb0 = *(f32x2*)p0; nb1 = *(f32x2*)p1; nb2 = *(f32x2*)p2;               \
        nb3 = *(f32x2*)p3; nb4 = *(f32x2*)p4;                                  \
        jt_nxt = jd[base];                                                     \
        const float frac = ptr - (float)base;                                  \
        const float r  = __builtin_amdgcn_exp2f(frac * C1f);                   \
        const float ri = __builtin_amdgcn_exp2f(-frac * C1f);                  \
        z0 = K2f * ri * ri; z1 = K1f * ri; z2 = 1.0f;                          \
        z3 = K1f * r;       z4 = K2f * r * r;                                  \
        inv = __builtin_amdgcn_rcpf(((z0 + z1) + (z2 + z3)) + z4);             \
    } else {                                                                   \
        /* WALK: weights carried, window = scattered regs + prefetched row */  \
        ptr = ptrW; base = baseW;                                              \
        nb0 = wnb0; nb1 = wnb1; nb2 = wnb2; nb3 = wnb3; nb4 = wnb4;            \
        p0 = wp0; p1 = wp1; p2 = wp2; p3 = wp3; p4 = wp4;                      \
        jt_nxt = jtW_pre;                                                      \
    }                                                                          \
    const f32x2 ctx = inv * (((nb0 * z0 + nb1 * z1) + (nb2 * z2 + nb3 * z3))   \
                             + nb4 * z4);                                      \
    f32x2 em; em[0] = (EC0); em[1] = (EC1);                                    \
    const f32x2 su = tanh2(em + cs * ctx + hid);                               \
    const f32x2 g  = su * inv;                                                 \
    const f32x2 m0v = nb0 + z0 * g, m1v = nb1 + z1 * g, m2v = nb2 + z2 * g,    \
                m3v = nb3 + z3 * g, m4v = nb4 + z4 * g;                        \
    *(f32x2*)p0 = m0v; *(f32x2*)p1 = m1v; *(f32x2*)p2 = m2v;                   \
    *(f32x2*)p3 = m3v; *(f32x2*)p4 = m4v;                                      \
    /* prep next walk candidate (reads after scatter; row base+3 untouched) */ \
    baseW = (base + 1) & 255;                                                  \
    ptrW  = ptr + 1.0f; if (ptrW >= 256.0f) ptrW -= 256.0f;                    \
    wnb0 = m1v; wnb1 = m2v; wnb2 = m3v; wnb3 = m4v;                            \
    wp0 = p1; wp1 = p2; wp2 = p3; wp3 = p4;                                    \
    wp4 = mem + (((base + 3) & 255) << 7) + 2 * l;                             \
    wnb4 = *(f32x2*)wp4;                                                       \
    jtW_pre = jd[baseW];                                                       \
    jt_cur  = jt_nxt;                                                          \
    /* reductions + LN + gate */                                               \
    float s1 = su[0] + su[1];                                                  \
    const f32x2 sq = su * su;  float s2 = sq[0] + sq[1];                       \
    const f32x2 sg = su * wg;  float s3 = sg[0] + sg[1];                       \
    wave_sum64_x3(s1, s2, s3);                                                 \
    const float mu   = s1 * (1.0f / En);                                       \
    const float var  = s2 * (1.0f / En) - mu * mu;                             \
    const float rstd = __builtin_amdgcn_rsqf(var + LN_EPS);                    \
    hid = (su - mu) * rstd * lnw + lnb;                                        \
    jl  = s3 + bgs;                                                            \
}

    for (int k = 0; k < 16; ++k) {
        for (int tbi = 0; tbi < 16; ++tbi) {
            const int tb = k * 16 + tbi;
            const int tp = tb + 2 > 255 ? 255 : tb + 2;
            float4 C0 = e40[tp << 7];
            float4 C1 = e41[tp << 7];
            SSTEP(A0.x, A1.x)
            SSTEP(A0.y, A1.y)
            SSTEP(A0.z, A1.z)
            SSTEP(A0.w, A1.w)
            A0 = B0; A1 = B1; B0 = C0; B1 = C1;
        }
        __syncthreads();               // chunk boundary (emb chunk k+2 ready)
    }
#undef SSTEP

    // epilogue: logits = hid @ Wo^T + bo
    mem[l] = hid[0]; mem[64 + l] = hid[1];
    __syncthreads();                   // final
    const float4* w4 = (const float4*)(Wo + l * En);
    const float4* h4 = (const float4*)mem;
    float a0 = 0.f, a1 = 0.f, a2 = 0.f, a3 = 0.f;
    #pragma unroll
    for (int i = 0; i < En / 4; ++i) {
        float4 wv = w4[i]; float4 hv = h4[i];
        a0 += wv.x * hv.x; a1 += wv.y * hv.y; a2 += wv.z * hv.z; a3 += wv.w * hv.w;
    }
    out[b * NOUTn + l] = (a0 + a1) + (a2 + a3) + bo[l];
}

// ===========================================================================
// Fallback (ws too small for the 128 MiB emb buffer): round-1 kernel.
// ===========================================================================
#define LDS_FLOATS (Pn*En + 2*En + 2*In + Pn)
#define LDS_BYTES  (LDS_FLOATS * 4)

__global__ __launch_bounds__(192, 1)
void ring_kernel(const float* __restrict__ x,
                 const float* __restrict__ pointer_init,
                 const float* __restrict__ W_in,
                 const float* __restrict__ b_in,
                 const float* __restrict__ ln_w,
                 const float* __restrict__ ln_b,
                 const float* __restrict__ jump_dest,
                 const float* __restrict__ Wg,
                 const float* __restrict__ bg,
                 const float* __restrict__ cs_ptr,
                 const float* __restrict__ Wo,
                 const float* __restrict__ bo,
                 float* __restrict__ out)
{
    extern __shared__ float lds[];
    float* mem  = lds;
    float* embb = mem + Pn * En;
    float* xb   = embb + 2 * En;
    float* jd   = xb + 2 * In;

    const int b   = blockIdx.x;
    const int tid = threadIdx.x;

    for (int i = tid; i < Pn * En; i += 192) mem[i] = 0.0f;
    for (int i = tid; i < Pn;      i += 192) jd[i]  = jump_dest[i];

    const float* xrow = x + (size_t)b * Tn * In;
    if (tid < 64) {
        xb[tid]      = xrow[tid];
        xb[In + tid] = xrow[In + tid];
    }
    __syncthreads();

    if (tid >= 64) {
        const int p = tid - 64;
        float wr[In];
        {
            const float4* w4 = (const float4*)(W_in + p * In);
            #pragma unroll
            for (int i = 0; i < In / 4; ++i) {
                float4 v = w4[i];
                wr[4*i+0] = v.x; wr[4*i+1] = v.y; wr[4*i+2] = v.z; wr[4*i+3] = v.w;
            }
        }
        const float bi = b_in[p];
        {
            float acc = bi;
            #pragma unroll
            for (int i = 0; i < In; ++i) acc += wr[i] * xb[i];
            embb[p] = tanhf(acc);
        }
        __syncthreads();
        for (int t = 0; t < Tn; ++t) {
            if (t + 1 < Tn) {
                const float* xc = xb + ((t + 1) & 1) * In;
                float acc = bi;
                #pragma unroll
                for (int i = 0; i < In; ++i) acc += wr[i] * xc[i];
                embb[((t + 1) & 1) * En + p] = tanhf(acc);
            }
            __syncthreads();
        }
    } else {
        const int l = tid;
        const float lnw0 = ln_w[l],      lnw1 = ln_w[l + 64];
        const float lnb0 = ln_b[l],      lnb1 = ln_b[l + 64];
        const float wg0  = Wg[l],        wg1  = Wg[l + 64];
        const float bgs  = bg[0];
        const float cs   = 1.0f / (1.0f + expf(-cs_ptr[0]));
        float hid0 = 0.0f, hid1 = 0.0f;
        float ptr  = pointer_init[b];
        __syncthreads();

        for (int t = 0; t < Tn; ++t) {
            const bool do_stage = (t + 2 < Tn);
            float xs = 0.0f;
            if (do_stage) xs = xrow[(t + 2) * In + l];

            const float* embc = embb + (t & 1) * En;

            int base = (int)floorf(ptr);
            base = base < 0 ? 0 : (base > Pn - 1 ? Pn - 1 : base);
            int cur = (int)ptr;
            cur = cur < 0 ? 0 : (cur > Pn - 1 ? Pn - 1 : cur);
            const float jt = jd[cur];

            const float frac = ptr - (float)base;
            int   idx[5];
            float wgt[5];
            float mx = -3.4e38f;
            #pragma unroll
            for (int j = 0; j < 5; ++j) {
                idx[j] = (base + j - 2 + Pn) & (Pn - 1);
                float d = (float)(j - 2) - frac;
                float s = -(d * d) * 0.125f;
                wgt[j] = s;
                mx = fmaxf(mx, s);
            }
            float se = 0.0f;
            #pragma unroll
            for (int j = 0; j < 5; ++j) { float ez = expf(wgt[j] - mx); wgt[j] = ez; se += ez; }
            const float inv = 1.0f / se;

            float nb0[5], nb1[5];
            #pragma unroll
            for (int j = 0; j < 5; ++j) {
                nb0[j] = mem[idx[j] * En + l];
                nb1[j] = mem[idx[j] * En + 64 + l];
            }
            float ctx0 = 0.0f, ctx1 = 0.0f;
            #pragma unroll
            for (int j = 0; j < 5; ++j) {
                const float w = wgt[j] * inv; wgt[j] = w;
                ctx0 += w * nb0[j];
                ctx1 += w * nb1[j];
            }

            const float su0 = tanhf(embc[l]      + cs * ctx0 + hid0);
            const float su1 = tanhf(embc[l + 64] + cs * ctx1 + hid1);

            #pragma unroll
            for (int j = 0; j < 5; ++j) {
                mem[idx[j] * En + l]      = nb0[j] + wgt[j] * su0;
                mem[idx[j] * En + 64 + l] = nb1[j] + wgt[j] * su1;
            }

            float s1 = su0 + su1;
            float s2 = su0 * su0 + su1 * su1;
            float s3 = su0 * wg0 + su1 * wg1;
            #pragma unroll
            for (int off = 32; off > 0; off >>= 1) {
                s1 += __shfl_xor(s1, off, 64);
                s2 += __shfl_xor(s2, off, 64);
                s3 += __shfl_xor(s3, off, 64);
            }

            const float mu   = s1 * (1.0f / En);
            const float var  = s2 * (1.0f / En) - mu * mu;
            const float rstd = rsqrtf(var + LN_EPS);
            hid0 = (su0 - mu) * rstd * lnw0 + lnb0;
            hid1 = (su1 - mu) * rstd * lnw1 + lnb1;

            const float jl = s3 + bgs;
            float walk = ptr + 1.0f;
            if (walk >= 256.0f) walk -= 256.0f;
            ptr = (jl > 0.0f) ? jt : walk;

            if (do_stage) xb[(t & 1) * In + l] = xs;
            __syncthreads();
        }
        embb[l]      = hid0;
        embb[l + 64] = hid1;
    }
    __syncthreads();

    if (tid < NOUTn) {
        const float* wrow = Wo + tid * En;
        float acc = bo[tid];
        #pragma unroll 4
        for (int e = 0; e < En; ++e) acc += embb[e] * wrow[e];
        out[b * NOUTn + tid] = acc;
    }
}

extern "C" void kernel_launch(void* const* d_in, const int* in_sizes, int n_in,
                              void* d_out, int out_size, void* d_ws, size_t ws_size,
                              hipStream_t stream) {
    const float* x            = (const float*)d_in[0];
    const float* pointer_init = (const float*)d_in[1];
    const float* W_in         = (const float*)d_in[2];
    const float* b_in         = (const float*)d_in[3];
    const float* ln_w         = (const float*)d_in[4];
    const float* ln_b         = (const float*)d_in[5];
    const float* jump_dest    = (const float*)d_in[6];
    const float* Wg           = (const float*)d_in[7];
    const float* bg           = (const float*)d_in[8];
    const float* cs           = (const float*)d_in[9];
    const float* Wo           = (const float*)d_in[10];
    const float* bo           = (const float*)d_in[11];
    float* out = (float*)d_out;

    const size_t emb_bytes = (size_t)Bn * Tn * En * sizeof(float);   // 128 MiB

    if (ws_size >= emb_bytes) {
        float* emb4 = (float*)d_ws;
        (void)hipFuncSetAttribute((const void*)fused_kernel,
                                  hipFuncAttributeMaxDynamicSharedMemorySize, LDSF_BYTES);
        fused_kernel<<<Bn, 192, LDSF_BYTES, stream>>>(
            x, pointer_init, W_in, b_in, ln_w, ln_b, jump_dest, Wg, bg, cs,
            Wo, bo, emb4, out);
    } else {
        (void)hipFuncSetAttribute((const void*)ring_kernel,
                                  hipFuncAttributeMaxDynamicSharedMemorySize, LDS_BYTES);
        ring_kernel<<<Bn, 192, LDS_BYTES, stream>>>(
            x, pointer_init, W_in, b_in, ln_w, ln_b, jump_dest, Wg, bg, cs, Wo, bo, out);
    }
}

// Round 8
// 504.602 us; speedup vs baseline: 1.4788x; 1.4788x over previous
//
#include <hip/hip_runtime.h>
#include <math.h>

// Problem constants (from reference)
#define Bn    256
#define Tn    1024
#define In    64
#define Pn    256
#define En    128
#define NOUTn 64
#define LN_EPS 1e-5f

// softmax factorization constants (TEMP=8):
// z_j ∝ exp((j-2)*frac/4) * exp(-(j-2)^2/8)  (common exp(-frac^2/8) cancels)
#define C1f 0.3606737602222409f     // log2(e)/4
#define K1f 0.8824969025845955f     // exp(-1/8)
#define K2f 0.6065306597126334f     // exp(-4/8)

typedef float f32x2 __attribute__((ext_vector_type(2)));

__device__ __forceinline__ float tanh_fast(float x) {
    float e = __builtin_amdgcn_exp2f(x * 2.88539008177793f);   // e^(2x)
    return 1.0f - 2.0f * __builtin_amdgcn_rcpf(e + 1.0f);
}
__device__ __forceinline__ f32x2 tanh2(f32x2 x) {
    f32x2 e;
    e[0] = __builtin_amdgcn_exp2f(x[0] * 2.88539008177793f);
    e[1] = __builtin_amdgcn_exp2f(x[1] * 2.88539008177793f);
    f32x2 r;
    r[0] = __builtin_amdgcn_rcpf(e[0] + 1.0f);
    r[1] = __builtin_amdgcn_rcpf(e[1] + 1.0f);
    return 1.0f - 2.0f * r;
}

template<int CTRL, int RMASK>
__device__ __forceinline__ float dpp_add(float x) {
    return x + __int_as_float(__builtin_amdgcn_update_dpp(
        0, __float_as_int(x), CTRL, RMASK, 0xF, false));
}
__device__ __forceinline__ void wave_sum64_x3(float& x, float& y, float& z) {
#define LVL(C, R) x = dpp_add<C, R>(x); y = dpp_add<C, R>(y); z = dpp_add<C, R>(z);
    LVL(0x111, 0xF)
    LVL(0x112, 0xF)
    LVL(0x114, 0xF)
    LVL(0x118, 0xF)
    LVL(0x142, 0xA)
    LVL(0x143, 0xC)
#undef LVL
    x = __int_as_float(__builtin_amdgcn_readlane(__float_as_int(x), 63));
    y = __int_as_float(__builtin_amdgcn_readlane(__float_as_int(y), 63));
    z = __int_as_float(__builtin_amdgcn_readlane(__float_as_int(z), 63));
}

// ===========================================================================
// FUSED kernel: 256 blocks x 192 threads (3 waves), one block per batch.
//   wave0 (consumer): scan4 step (best measured) over 16 chunks of 64 t,
//                     emb read from ws global with 2-block register prefetch.
//   waves1-2 (producers): embgemm-style register tile for chunk k+2 while
//                     the consumer scans chunk k. Thread = 8 consecutive t
//                     x 8 strided e; x AND W loaded with PER-LANE VMEM
//                     dwordx4 (lane-derived t_oct/e0 -> never scalarized;
//                     this is the R7 fix: wave-uniform x loads had been
//                     lowered to serialized SMEM s_load batches).
// Producer chunk ~4 us << consumer chunk ~23 us -> producers sleep at the
// per-chunk barrier; 3 waves sit on 3 different SIMDs (no issue contention).
// Producer accumulation order is bit-identical to R5's embgemm kernel.
// ===========================================================================
#define LDSF_FLOATS (Pn * En + Pn)
#define LDSF_BYTES  (LDSF_FLOATS * 4)

__global__ __launch_bounds__(192, 1)
void fused_kernel(const float* __restrict__ x,
                  const float* __restrict__ pointer_init,
                  const float* __restrict__ W_in, const float* __restrict__ b_in,
                  const float* __restrict__ ln_w, const float* __restrict__ ln_b,
                  const float* __restrict__ jump_dest,
                  const float* __restrict__ Wg,  const float* __restrict__ bg,
                  const float* __restrict__ cs_ptr,
                  const float* __restrict__ Wo,  const float* __restrict__ bo,
                  float* __restrict__ emb4, float* __restrict__ out) {
    extern __shared__ float lds[];
    float* mem = lds;              // ring: [row][2*l + c], channel pair per lane
    float* jd  = lds + Pn * En;    // jump_dest copy

    const int b   = blockIdx.x;
    const int tid = threadIdx.x;

    if (tid >= 64) {
        // ================= PRODUCERS (waves 1,2): embgemm register tile =======
        const int p     = tid - 64;        // 0..127
        const int t_oct = p >> 4;          // 0..7  (8 consecutive t each)
        const int e0    = p & 15;          // e = e0 + 16*j, j = 0..7
        float be[8];
        #pragma unroll
        for (int j = 0; j < 8; ++j) be[j] = b_in[e0 + 16 * j];

        const float* xb   = x + (size_t)b * Tn * In;
        float*       dstb = emb4 + ((size_t)b << 17);

#define PRODUCE(K) {                                                          \
    const int t0 = (K) * 64 + t_oct * 8;                                      \
    const float4* xr = (const float4*)(xb + t0 * In);   /* per-lane addr */   \
    float acc[8][8];                                                          \
    _Pragma("unroll")                                                         \
    for (int tt = 0; tt < 8; ++tt)                                            \
        _Pragma("unroll")                                                     \
        for (int j = 0; j < 8; ++j) acc[tt][j] = 0.f;                         \
    for (int i4 = 0; i4 < 16; ++i4) {                                         \
        float4 xv[8];                                                         \
        _Pragma("unroll")                                                     \
        for (int tt = 0; tt < 8; ++tt) xv[tt] = xr[tt * 16 + i4];             \
        float4 wf[8];                                                         \
        _Pragma("unroll")                                                     \
        for (int j = 0; j < 8; ++j)                                           \
            wf[j] = *(const float4*)(W_in + (e0 + 16 * j) * In + i4 * 4);     \
        _Pragma("unroll")                                                     \
        for (int tt = 0; tt < 8; ++tt)                                        \
            _Pragma("unroll")                                                 \
            for (int j = 0; j < 8; ++j) {                                     \
                acc[tt][j] += xv[tt].x * wf[j].x;                             \
                acc[tt][j] += xv[tt].y * wf[j].y;                             \
                acc[tt][j] += xv[tt].z * wf[j].z;                             \
                acc[tt][j] += xv[tt].w * wf[j].w;                             \
            }                                                                 \
    }                                                                         \
    const int tb0 = t0 >> 2;                                                  \
    _Pragma("unroll")                                                         \
    for (int j = 0; j < 8; ++j) {                                             \
        const int e = e0 + 16 * j;                                            \
        _Pragma("unroll")                                                     \
        for (int tb = 0; tb < 2; ++tb) {                                      \
            float4 o;                                                         \
            o.x = tanh_fast(acc[tb * 4 + 0][j] + be[j]);                      \
            o.y = tanh_fast(acc[tb * 4 + 1][j] + be[j]);                      \
            o.z = tanh_fast(acc[tb * 4 + 2][j] + be[j]);                      \
            o.w = tanh_fast(acc[tb * 4 + 3][j] + be[j]);                      \
            *(float4*)&dstb[((size_t)(tb0 + tb) * 128 + e) * 4] = o;          \
        }                                                                     \
    }                                                                         \
}
        PRODUCE(0)
        PRODUCE(1)
        __syncthreads();                   // #1: chunks 0,1 ready
        for (int k = 0; k < 16; ++k) {
            if (k + 2 < 16) PRODUCE(k + 2)
            __syncthreads();               // chunk boundary
        }
#undef PRODUCE
        __syncthreads();                   // final: hid broadcast
        return;
    }

    // ================= CONSUMER (wave 0): scan4 step, chunked =================
    const int l = tid;

    float4* m4 = (float4*)mem;
    for (int i = l; i < Pn * En / 4; i += 64) m4[i] = make_float4(0.f, 0.f, 0.f, 0.f);
    for (int i = l; i < Pn; i += 64) jd[i] = jump_dest[i];

    const f32x2 lnw = {ln_w[l], ln_w[l + 64]};
    const f32x2 lnb = {ln_b[l], ln_b[l + 64]};
    const f32x2 wg  = {Wg[l],   Wg[l + 64]};
    const float bgs = bg[0];
    const float cs  = 1.0f / (1.0f + expf(-cs_ptr[0]));
    f32x2 hid = {0.f, 0.f};

    float* myb = mem + 2 * l;

    // ---- pipeline state (scan4: forced jump to pointer_init at t=0) ----
    float jl      = 1.0f;
    float jt_cur  = pointer_init[b];
    float ptrW    = 0.f;
    int   baseW   = 0;
    float jtW_pre = 0.f;
    float z0 = 0.f, z1 = 0.f, z2 = 1.f, z3 = 0.f, z4 = 0.f, inv = 1.f;
    f32x2 wnb0 = {0,0}, wnb1 = {0,0}, wnb2 = {0,0}, wnb3 = {0,0}, wnb4 = {0,0};
    float *wp0 = myb, *wp1 = myb, *wp2 = myb, *wp3 = myb, *wp4 = myb;

    __syncthreads();                       // #1: emb chunks 0,1 ready

    const float4* e40 = (const float4*)(emb4 + ((size_t)b << 17)) + l;   // ch l
    const float4* e41 = e40 + 64;                                        // ch l+64
    float4 A0 = e40[0],   A1 = e41[0];
    float4 B0 = e40[128], B1 = e41[128];

#define SSTEP(EC0, EC1) {                                                      \
    float ptr; int base;                                                       \
    f32x2 nb0, nb1, nb2, nb3, nb4;                                             \
    float *p0, *p1, *p2, *p3, *p4;                                             \
    float jt_nxt;                                                              \
    if (__builtin_amdgcn_readfirstlane(__float_as_int(jl)) > 0) {              \
        /* JUMP: full gather + weight recompute */                             \
        ptr  = jt_cur;                                                         \
        base = (int)ptr; base = base > 255 ? 255 : base;                       \
        p0 = mem + (((base + 254) & 255) << 7) + 2 * l;                        \
        p1 = mem + (((base + 255) & 255) << 7) + 2 * l;                        \
        p2 = mem + (base << 7) + 2 * l;                                        \
        p3 = mem + (((base + 1) & 255) << 7) + 2 * l;                          \
        p4 = mem + (((base + 2) & 255) << 7) + 2 * l;                          \
        nb0 = *(f32x2*)p0; nb1 = *(f32x2*)p1; nb2 = *(f32x2*)p2;               \
        nb3 = *(f32x2*)p3; nb4 = *(f32x2*)p4;                                  \
        jt_nxt = jd[base];                                                     \
        const float frac = ptr - (float)base;                                  \
        const float r  = __builtin_amdgcn_exp2f(frac * C1f);                   \
        const float ri = __builtin_amdgcn_exp2f(-frac * C1f);                  \
        z0 = K2f * ri * ri; z1 = K1f * ri; z2 = 1.0f;                          \
        z3 = K1f * r;       z4 = K2f * r * r;                                  \
        inv = __builtin_amdgcn_rcpf(((z0 + z1) + (z2 + z3)) + z4);             \
    } else {                                                                   \
        /* WALK: weights carried, window = scattered regs + prefetched row */  \
        ptr = ptrW; base = baseW;                                              \
        nb0 = wnb0; nb1 = wnb1; nb2 = wnb2; nb3 = wnb3; nb4 = wnb4;            \
        p0 = wp0; p1 = wp1; p2 = wp2; p3 = wp3; p4 = wp4;                      \
        jt_nxt = jtW_pre;                                                      \
    }                                                                          \
    const f32x2 ctx = inv * (((nb0 * z0 + nb1 * z1) + (nb2 * z2 + nb3 * z3))   \
                             + nb4 * z4);                                      \
    f32x2 em; em[0] = (EC0); em[1] = (EC1);                                    \
    const f32x2 su = tanh2(em + cs * ctx + hid);                               \
    const f32x2 g  = su * inv;                                                 \
    const f32x2 m0v = nb0 + z0 * g, m1v = nb1 + z1 * g, m2v = nb2 + z2 * g,    \
                m3v = nb3 + z3 * g, m4v = nb4 + z4 * g;                        \
    *(f32x2*)p0 = m0v; *(f32x2*)p1 = m1v; *(f32x2*)p2 = m2v;                   \
    *(f32x2*)p3 = m3v; *(f32x2*)p4 = m4v;                                      \
    /* prep next walk candidate (reads after scatter; row base+3 untouched) */ \
    baseW = (base + 1) & 255;                                                  \
    ptrW  = ptr + 1.0f; if (ptrW >= 256.0f) ptrW -= 256.0f;                    \
    wnb0 = m1v; wnb1 = m2v; wnb2 = m3v; wnb3 = m4v;                            \
    wp0 = p1; wp1 = p2; wp2 = p3; wp3 = p4;                                    \
    wp4 = mem + (((base + 3) & 255) << 7) + 2 * l;                             \
    wnb4 = *(f32x2*)wp4;                                                       \
    jtW_pre = jd[baseW];                                                       \
    jt_cur  = jt_nxt;                                                          \
    /* reductions + LN + gate */                                               \
    float s1 = su[0] + su[1];                                                  \
    const f32x2 sq = su * su;  float s2 = sq[0] + sq[1];                       \
    const f32x2 sg = su * wg;  float s3 = sg[0] + sg[1];                       \
    wave_sum64_x3(s1, s2, s3);                                                 \
    const float mu   = s1 * (1.0f / En);                                       \
    const float var  = s2 * (1.0f / En) - mu * mu;                             \
    const float rstd = __builtin_amdgcn_rsqf(var + LN_EPS);                    \
    hid = (su - mu) * rstd * lnw + lnb;                                        \
    jl  = s3 + bgs;                                                            \
}

    for (int k = 0; k < 16; ++k) {
        for (int tbi = 0; tbi < 16; ++tbi) {
            const int tb = k * 16 + tbi;
            const int tp = tb + 2 > 255 ? 255 : tb + 2;
            float4 C0 = e40[tp << 7];
            float4 C1 = e41[tp << 7];
            SSTEP(A0.x, A1.x)
            SSTEP(A0.y, A1.y)
            SSTEP(A0.z, A1.z)
            SSTEP(A0.w, A1.w)
            A0 = B0; A1 = B1; B0 = C0; B1 = C1;
        }
        __syncthreads();               // chunk boundary (emb chunk k+2 ready)
    }
#undef SSTEP

    // epilogue: logits = hid @ Wo^T + bo
    mem[l] = hid[0]; mem[64 + l] = hid[1];
    __syncthreads();                   // final
    const float4* w4 = (const float4*)(Wo + l * En);
    const float4* h4 = (const float4*)mem;
    float a0 = 0.f, a1 = 0.f, a2 = 0.f, a3 = 0.f;
    #pragma unroll
    for (int i = 0; i < En / 4; ++i) {
        float4 wv = w4[i]; float4 hv = h4[i];
        a0 += wv.x * hv.x; a1 += wv.y * hv.y; a2 += wv.z * hv.z; a3 += wv.w * hv.w;
    }
    out[b * NOUTn + l] = (a0 + a1) + (a2 + a3) + bo[l];
}

// ===========================================================================
// Fallback (ws too small for the 128 MiB emb buffer): round-1 kernel.
// ===========================================================================
#define LDS_FLOATS (Pn*En + 2*En + 2*In + Pn)
#define LDS_BYTES  (LDS_FLOATS * 4)

__global__ __launch_bounds__(192, 1)
void ring_kernel(const float* __restrict__ x,
                 const float* __restrict__ pointer_init,
                 const float* __restrict__ W_in,
                 const float* __restrict__ b_in,
                 const float* __restrict__ ln_w,
                 const float* __restrict__ ln_b,
                 const float* __restrict__ jump_dest,
                 const float* __restrict__ Wg,
                 const float* __restrict__ bg,
                 const float* __restrict__ cs_ptr,
                 const float* __restrict__ Wo,
                 const float* __restrict__ bo,
                 float* __restrict__ out)
{
    extern __shared__ float lds[];
    float* mem  = lds;
    float* embb = mem + Pn * En;
    float* xb   = embb + 2 * En;
    float* jd   = xb + 2 * In;

    const int b   = blockIdx.x;
    const int tid = threadIdx.x;

    for (int i = tid; i < Pn * En; i += 192) mem[i] = 0.0f;
    for (int i = tid; i < Pn;      i += 192) jd[i]  = jump_dest[i];

    const float* xrow = x + (size_t)b * Tn * In;
    if (tid < 64) {
        xb[tid]      = xrow[tid];
        xb[In + tid] = xrow[In + tid];
    }
    __syncthreads();

    if (tid >= 64) {
        const int p = tid - 64;
        float wr[In];
        {
            const float4* w4 = (const float4*)(W_in + p * In);
            #pragma unroll
            for (int i = 0; i < In / 4; ++i) {
                float4 v = w4[i];
                wr[4*i+0] = v.x; wr[4*i+1] = v.y; wr[4*i+2] = v.z; wr[4*i+3] = v.w;
            }
        }
        const float bi = b_in[p];
        {
            float acc = bi;
            #pragma unroll
            for (int i = 0; i < In; ++i) acc += wr[i] * xb[i];
            embb[p] = tanhf(acc);
        }
        __syncthreads();
        for (int t = 0; t < Tn; ++t) {
            if (t + 1 < Tn) {
                const float* xc = xb + ((t + 1) & 1) * In;
                float acc = bi;
                #pragma unroll
                for (int i = 0; i < In; ++i) acc += wr[i] * xc[i];
                embb[((t + 1) & 1) * En + p] = tanhf(acc);
            }
            __syncthreads();
        }
    } else {
        const int l = tid;
        const float lnw0 = ln_w[l],      lnw1 = ln_w[l + 64];
        const float lnb0 = ln_b[l],      lnb1 = ln_b[l + 64];
        const float wg0  = Wg[l],        wg1  = Wg[l + 64];
        const float bgs  = bg[0];
        const float cs   = 1.0f / (1.0f + expf(-cs_ptr[0]));
        float hid0 = 0.0f, hid1 = 0.0f;
        float ptr  = pointer_init[b];
        __syncthreads();

        for (int t = 0; t < Tn; ++t) {
            const bool do_stage = (t + 2 < Tn);
            float xs = 0.0f;
            if (do_stage) xs = xrow[(t + 2) * In + l];

            const float* embc = embb + (t & 1) * En;

            int base = (int)floorf(ptr);
            base = base < 0 ? 0 : (base > Pn - 1 ? Pn - 1 : base);
            int cur = (int)ptr;
            cur = cur < 0 ? 0 : (cur > Pn - 1 ? Pn - 1 : cur);
            const float jt = jd[cur];

            const float frac = ptr - (float)base;
            int   idx[5];
            float wgt[5];
            float mx = -3.4e38f;
            #pragma unroll
            for (int j = 0; j < 5; ++j) {
                idx[j] = (base + j - 2 + Pn) & (Pn - 1);
                float d = (float)(j - 2) - frac;
                float s = -(d * d) * 0.125f;
                wgt[j] = s;
                mx = fmaxf(mx, s);
            }
            float se = 0.0f;
            #pragma unroll
            for (int j = 0; j < 5; ++j) { float ez = expf(wgt[j] - mx); wgt[j] = ez; se += ez; }
            const float inv = 1.0f / se;

            float nb0[5], nb1[5];
            #pragma unroll
            for (int j = 0; j < 5; ++j) {
                nb0[j] = mem[idx[j] * En + l];
                nb1[j] = mem[idx[j] * En + 64 + l];
            }
            float ctx0 = 0.0f, ctx1 = 0.0f;
            #pragma unroll
            for (int j = 0; j < 5; ++j) {
                const float w = wgt[j] * inv; wgt[j] = w;
                ctx0 += w * nb0[j];
                ctx1 += w * nb1[j];
            }

            const float su0 = tanhf(embc[l]      + cs * ctx0 + hid0);
            const float su1 = tanhf(embc[l + 64] + cs * ctx1 + hid1);

            #pragma unroll
            for (int j = 0; j < 5; ++j) {
                mem[idx[j] * En + l]      = nb0[j] + wgt[j] * su0;
                mem[idx[j] * En + 64 + l] = nb1[j] + wgt[j] * su1;
            }

            float s1 = su0 + su1;
            float s2 = su0 * su0 + su1 * su1;
            float s3 = su0 * wg0 + su1 * wg1;
            #pragma unroll
            for (int off = 32; off > 0; off >>= 1) {
                s1 += __shfl_xor(s1, off, 64);
                s2 += __shfl_xor(s2, off, 64);
                s3 += __shfl_xor(s3, off, 64);
            }

            const float mu   = s1 * (1.0f / En);
            const float var  = s2 * (1.0f / En) - mu * mu;
            const float rstd = rsqrtf(var + LN_EPS);
            hid0 = (su0 - mu) * rstd * lnw0 + lnb0;
            hid1 = (su1 - mu) * rstd * lnw1 + lnb1;

            const float jl = s3 + bgs;
            float walk = ptr + 1.0f;
            if (walk >= 256.0f) walk -= 256.0f;
            ptr = (jl > 0.0f) ? jt : walk;

            if (do_stage) xb[(t & 1) * In + l] = xs;
            __syncthreads();
        }
        embb[l]      = hid0;
        embb[l + 64] = hid1;
    }
    __syncthreads();

    if (tid < NOUTn) {
        const float* wrow = Wo + tid * En;
        float acc = bo[tid];
        #pragma unroll 4
        for (int e = 0; e < En; ++e) acc += embb[e] * wrow[e];
        out[b * NOUTn + tid] = acc;
    }
}

extern "C" void kernel_launch(void* const* d_in, const int* in_sizes, int n_in,
                              void* d_out, int out_size, void* d_ws, size_t ws_size,
                              hipStream_t stream) {
    const float* x            = (const float*)d_in[0];
    const float* pointer_init = (const float*)d_in[1];
    const float* W_in         = (const float*)d_in[2];
    const float* b_in         = (const float*)d_in[3];
    const float* ln_w         = (const float*)d_in[4];
    const float* ln_b         = (const float*)d_in[5];
    const float* jump_dest    = (const float*)d_in[6];
    const float* Wg           = (const float*)d_in[7];
    const float* bg           = (const float*)d_in[8];
    const float* cs           = (const float*)d_in[9];
    const float* Wo           = (const float*)d_in[10];
    const float* bo           = (const float*)d_in[11];
    float* out = (float*)d_out;

    const size_t emb_bytes = (size_t)Bn * Tn * En * sizeof(float);   // 128 MiB

    if (ws_size >= emb_bytes) {
        float* emb4 = (float*)d_ws;
        (void)hipFuncSetAttribute((const void*)fused_kernel,
                                  hipFuncAttributeMaxDynamicSharedMemorySize, LDSF_BYTES);
        fused_kernel<<<Bn, 192, LDSF_BYTES, stream>>>(
            x, pointer_init, W_in, b_in, ln_w, ln_b, jump_dest, Wg, bg, cs,
            Wo, bo, emb4, out);
    } else {
        (void)hipFuncSetAttribute((const void*)ring_kernel,
                                  hipFuncAttributeMaxDynamicSharedMemorySize, LDS_BYTES);
        ring_kernel<<<Bn, 192, LDS_BYTES, stream>>>(
            x, pointer_init, W_in, b_in, ln_w, ln_b, jump_dest, Wg, bg, cs, Wo, bo, out);
    }
}

// Round 9
// 472.654 us; speedup vs baseline: 1.5787x; 1.0676x over previous
//
#include <hip/hip_runtime.h>
#include <math.h>

// Problem constants (from reference)
#define Bn    256
#define Tn    1024
#define In    64
#define Pn    256
#define En    128
#define NOUTn 64
#define LN_EPS 1e-5f

// softmax factorization constants (TEMP=8):
// z_j ∝ exp((j-2)*frac/4) * exp(-(j-2)^2/8)  (common exp(-frac^2/8) cancels)
#define C1f 0.3606737602222409f     // log2(e)/4
#define K1f 0.8824969025845955f     // exp(-1/8)
#define K2f 0.6065306597126334f     // exp(-4/8)

typedef float f32x2 __attribute__((ext_vector_type(2)));

__device__ __forceinline__ float tanh_fast(float x) {
    float e = __builtin_amdgcn_exp2f(x * 2.88539008177793f);   // e^(2x)
    return 1.0f - 2.0f * __builtin_amdgcn_rcpf(e + 1.0f);
}
__device__ __forceinline__ f32x2 tanh2(f32x2 x) {
    f32x2 e;
    e[0] = __builtin_amdgcn_exp2f(x[0] * 2.88539008177793f);
    e[1] = __builtin_amdgcn_exp2f(x[1] * 2.88539008177793f);
    f32x2 r;
    r[0] = __builtin_amdgcn_rcpf(e[0] + 1.0f);
    r[1] = __builtin_amdgcn_rcpf(e[1] + 1.0f);
    return 1.0f - 2.0f * r;
}

template<int CTRL, int RMASK>
__device__ __forceinline__ float dpp_add(float x) {
    return x + __int_as_float(__builtin_amdgcn_update_dpp(
        0, __float_as_int(x), CTRL, RMASK, 0xF, false));
}
__device__ __forceinline__ void wave_sum64_x3(float& x, float& y, float& z) {
#define LVL(C, R) x = dpp_add<C, R>(x); y = dpp_add<C, R>(y); z = dpp_add<C, R>(z);
    LVL(0x111, 0xF)
    LVL(0x112, 0xF)
    LVL(0x114, 0xF)
    LVL(0x118, 0xF)
    LVL(0x142, 0xA)
    LVL(0x143, 0xC)
#undef LVL
    x = __int_as_float(__builtin_amdgcn_readlane(__float_as_int(x), 63));
    y = __int_as_float(__builtin_amdgcn_readlane(__float_as_int(y), 63));
    z = __int_as_float(__builtin_amdgcn_readlane(__float_as_int(z), 63));
}

// ===========================================================================
// FULLY-FUSED kernel, zero workspace: 256 blocks x 192 threads (3 waves).
//   wave0 (consumer): scan4 step over 64 chunks of 16 timesteps; emb read
//                     from a triple-buffered LDS stage (one ds_read_b128
//                     pair per 4-step group, prefetched one group ahead).
//   waves1-2 (producers): emb chunk k+2 into stage buf[(k+2)%3] while the
//                     consumer scans chunk k from buf[k%3]. Thread tile
//                     4t x 4e; x and W_in loaded with per-lane VMEM dwordx4
//                     (lane-derived tq/eidx -> never scalarized). Per-dot
//                     accumulation order bit-identical to R8's producer.
// Triple buffering makes the consumer's cross-chunk group prefetch race-free:
// during chunk k, producers touch only buf[(k+2)%3]; consumer reads buf[k%3]
// and prefetches at most into buf[(k+1)%3].
// LDS: ring 128 KB + jd 1 KB + stage 3x8 KB = 153 KB (fits 160 KB).
// No global emb traffic at all (R8 paid a 128 MiB HBM round-trip for it).
// ===========================================================================
#define STAGE_FLOATS (3 * 16 * En)                 // 6144
#define LDSF_FLOATS  (Pn * En + Pn + STAGE_FLOATS) // 39168
#define LDSF_BYTES   (LDSF_FLOATS * 4)             // 156672

__global__ __launch_bounds__(192, 1)
void fused2_kernel(const float* __restrict__ x,
                   const float* __restrict__ pointer_init,
                   const float* __restrict__ W_in, const float* __restrict__ b_in,
                   const float* __restrict__ ln_w, const float* __restrict__ ln_b,
                   const float* __restrict__ jump_dest,
                   const float* __restrict__ Wg,  const float* __restrict__ bg,
                   const float* __restrict__ cs_ptr,
                   const float* __restrict__ Wo,  const float* __restrict__ bo,
                   float* __restrict__ out) {
    extern __shared__ float lds[];
    float* mem = lds;                    // ring: [row][2*l + c]
    float* jd  = lds + Pn * En;          // jump_dest copy
    float* stg = lds + Pn * En + Pn;     // stage: [buf3][tq4][e128][t4]

    const int b   = blockIdx.x;
    const int tid = threadIdx.x;

    if (tid >= 64) {
        // ================= PRODUCERS (waves 1,2): 4t x 4e register tile ======
        const int p    = tid - 64;        // 0..127
        const int tq   = p >> 5;          // 0..3 : which 4-t group of the chunk
        const int eidx = p & 31;          // e = eidx + 32*j, j=0..3
        float be[4];
        #pragma unroll
        for (int j = 0; j < 4; ++j) be[j] = b_in[eidx + 32 * j];
        const float* xb = x + (size_t)b * Tn * In;

#define PRODUCE(K, BUF) {                                                     \
    const int t0 = (K) * 16 + tq * 4;                                         \
    const float4* xr = (const float4*)(xb + t0 * In);   /* per-lane addr */   \
    float acc[4][4];                                                          \
    _Pragma("unroll")                                                         \
    for (int tt = 0; tt < 4; ++tt)                                            \
        _Pragma("unroll")                                                     \
        for (int j = 0; j < 4; ++j) acc[tt][j] = 0.f;                         \
    _Pragma("unroll")                                                         \
    for (int i4 = 0; i4 < 16; ++i4) {                                         \
        float4 xv[4];                                                         \
        _Pragma("unroll")                                                     \
        for (int tt = 0; tt < 4; ++tt) xv[tt] = xr[tt * 16 + i4];             \
        float4 wf[4];                                                         \
        _Pragma("unroll")                                                     \
        for (int j = 0; j < 4; ++j)                                           \
            wf[j] = *(const float4*)(W_in + (eidx + 32 * j) * In + i4 * 4);   \
        _Pragma("unroll")                                                     \
        for (int tt = 0; tt < 4; ++tt)                                        \
            _Pragma("unroll")                                                 \
            for (int j = 0; j < 4; ++j) {                                     \
                acc[tt][j] += xv[tt].x * wf[j].x;                             \
                acc[tt][j] += xv[tt].y * wf[j].y;                             \
                acc[tt][j] += xv[tt].z * wf[j].z;                             \
                acc[tt][j] += xv[tt].w * wf[j].w;                             \
            }                                                                 \
    }                                                                         \
    float* sg = stg + (BUF) * 2048 + tq * 512;                                \
    _Pragma("unroll")                                                         \
    for (int j = 0; j < 4; ++j) {                                             \
        float4 o;                                                             \
        o.x = tanh_fast(acc[0][j] + be[j]);                                   \
        o.y = tanh_fast(acc[1][j] + be[j]);                                   \
        o.z = tanh_fast(acc[2][j] + be[j]);                                   \
        o.w = tanh_fast(acc[3][j] + be[j]);                                   \
        *(float4*)(sg + (eidx + 32 * j) * 4) = o;                             \
    }                                                                         \
}
        PRODUCE(0, 0)
        PRODUCE(1, 1)
        __syncthreads();                   // #1: chunks 0,1 staged
        int buf = 2;
        for (int k = 0; k < 64; ++k) {
            if (k + 2 < 64) {
                PRODUCE(k + 2, buf)
                buf = (buf == 2) ? 0 : buf + 1;
            }
            __syncthreads();               // chunk boundary
        }
#undef PRODUCE
        __syncthreads();                   // final: hid broadcast
        return;
    }

    // ================= CONSUMER (wave 0): scan4 step, LDS-staged emb =========
    const int l = tid;

    float4* m4 = (float4*)mem;
    for (int i = l; i < Pn * En / 4; i += 64) m4[i] = make_float4(0.f, 0.f, 0.f, 0.f);
    for (int i = l; i < Pn; i += 64) jd[i] = jump_dest[i];

    const f32x2 lnw = {ln_w[l], ln_w[l + 64]};
    const f32x2 lnb = {ln_b[l], ln_b[l + 64]};
    const f32x2 wg  = {Wg[l],   Wg[l + 64]};
    const float bgs = bg[0];
    const float cs  = 1.0f / (1.0f + expf(-cs_ptr[0]));
    f32x2 hid = {0.f, 0.f};

    float* myb = mem + 2 * l;

    // ---- pipeline state (scan4: forced jump to pointer_init at t=0) ----
    float jl      = 1.0f;
    float jt_cur  = pointer_init[b];
    float ptrW    = 0.f;
    int   baseW   = 0;
    float jtW_pre = 0.f;
    float z0 = 0.f, z1 = 0.f, z2 = 1.f, z3 = 0.f, z4 = 0.f, inv = 1.f;
    f32x2 wnb0 = {0,0}, wnb1 = {0,0}, wnb2 = {0,0}, wnb3 = {0,0}, wnb4 = {0,0};
    float *wp0 = myb, *wp1 = myb, *wp2 = myb, *wp3 = myb, *wp4 = myb;

    __syncthreads();                       // #1: emb chunks 0,1 staged

    // A = current 4-step group registers (group tb=0)
    const float* sa0 = stg + 4 * l;        // buf0, group 0, ch l
    float4 A0 = *(const float4*)sa0;
    float4 A1 = *(const float4*)(sa0 + 256);

#define SSTEP(EC0, EC1) {                                                      \
    float ptr; int base;                                                       \
    f32x2 nb0, nb1, nb2, nb3, nb4;                                             \
    float *p0, *p1, *p2, *p3, *p4;                                             \
    float jt_nxt;                                                              \
    if (__builtin_amdgcn_readfirstlane(__float_as_int(jl)) > 0) {              \
        /* JUMP: full gather + weight recompute */                             \
        ptr  = jt_cur;                                                         \
        base = (int)ptr; base = base > 255 ? 255 : base;                       \
        p0 = mem + (((base + 254) & 255) << 7) + 2 * l;                        \
        p1 = mem + (((base + 255) & 255) << 7) + 2 * l;                        \
        p2 = mem + (base << 7) + 2 * l;                                        \
        p3 = mem + (((base + 1) & 255) << 7) + 2 * l;                          \
        p4 = mem + (((base + 2) & 255) << 7) + 2 * l;                          \
        nb0 = *(f32x2*)p0; nb1 = *(f32x2*)p1; nb2 = *(f32x2*)p2;               \
        nb3 = *(f32x2*)p3; nb4 = *(f32x2*)p4;                                  \
        jt_nxt = jd[base];                                                     \
        const float frac = ptr - (float)base;                                  \
        const float r  = __builtin_amdgcn_exp2f(frac * C1f);                   \
        const float ri = __builtin_amdgcn_exp2f(-frac * C1f);                  \
        z0 = K2f * ri * ri; z1 = K1f * ri; z2 = 1.0f;                          \
        z3 = K1f * r;       z4 = K2f * r * r;                                  \
        inv = __builtin_amdgcn_rcpf(((z0 + z1) + (z2 + z3)) + z4);             \
    } else {                                                                   \
        /* WALK: weights carried, window = scattered regs + prefetched row */  \
        ptr = ptrW; base = baseW;                                              \
        nb0 = wnb0; nb1 = wnb1; nb2 = wnb2; nb3 = wnb3; nb4 = wnb4;            \
        p0 = wp0; p1 = wp1; p2 = wp2; p3 = wp3; p4 = wp4;                      \
        jt_nxt = jtW_pre;                                                      \
    }                                                                          \
    const f32x2 ctx = inv * (((nb0 * z0 + nb1 * z1) + (nb2 * z2 + nb3 * z3))   \
                             + nb4 * z4);                                      \
    f32x2 em; em[0] = (EC0); em[1] = (EC1);                                    \
    const f32x2 su = tanh2(em + cs * ctx + hid);                               \
    const f32x2 g  = su * inv;                                                 \
    const f32x2 m0v = nb0 + z0 * g, m1v = nb1 + z1 * g, m2v = nb2 + z2 * g,    \
                m3v = nb3 + z3 * g, m4v = nb4 + z4 * g;                        \
    *(f32x2*)p0 = m0v; *(f32x2*)p1 = m1v; *(f32x2*)p2 = m2v;                   \
    *(f32x2*)p3 = m3v; *(f32x2*)p4 = m4v;                                      \
    /* prep next walk candidate (reads after scatter; row base+3 untouched) */ \
    baseW = (base + 1) & 255;                                                  \
    ptrW  = ptr + 1.0f; if (ptrW >= 256.0f) ptrW -= 256.0f;                    \
    wnb0 = m1v; wnb1 = m2v; wnb2 = m3v; wnb3 = m4v;                            \
    wp0 = p1; wp1 = p2; wp2 = p3; wp3 = p4;                                    \
    wp4 = mem + (((base + 3) & 255) << 7) + 2 * l;                             \
    wnb4 = *(f32x2*)wp4;                                                       \
    jtW_pre = jd[baseW];                                                       \
    jt_cur  = jt_nxt;                                                          \
    /* reductions + LN + gate */                                               \
    float s1 = su[0] + su[1];                                                  \
    const f32x2 sq = su * su;  float s2 = sq[0] + sq[1];                       \
    const f32x2 sg = su * wg;  float s3 = sg[0] + sg[1];                       \
    wave_sum64_x3(s1, s2, s3);                                                 \
    const float mu   = s1 * (1.0f / En);                                       \
    const float var  = s2 * (1.0f / En) - mu * mu;                             \
    const float rstd = __builtin_amdgcn_rsqf(var + LN_EPS);                    \
    hid = (su - mu) * rstd * lnw + lnb;                                        \
    jl  = s3 + bgs;                                                            \
}

    for (int k = 0; k < 64; ++k) {
        #pragma unroll
        for (int g = 0; g < 4; ++g) {
            const int tb  = k * 4 + g;
            int tbn = tb + 1; if (tbn > 255) tbn = 255;
            // prefetch next group: buf[(tbn>>2)%3] is never producer-active
            const float* sb = stg + ((tbn >> 2) % 3) * 2048 + (tbn & 3) * 512 + 4 * l;
            float4 B0 = *(const float4*)sb;
            float4 B1 = *(const float4*)(sb + 256);
            SSTEP(A0.x, A1.x)
            SSTEP(A0.y, A1.y)
            SSTEP(A0.z, A1.z)
            SSTEP(A0.w, A1.w)
            A0 = B0; A1 = B1;
        }
        __syncthreads();               // chunk boundary (chunk k+2 staged)
    }
#undef SSTEP

    // epilogue: logits = hid @ Wo^T + bo
    mem[l] = hid[0]; mem[64 + l] = hid[1];
    __syncthreads();                   // final
    const float4* w4 = (const float4*)(Wo + l * En);
    const float4* h4 = (const float4*)mem;
    float a0 = 0.f, a1 = 0.f, a2 = 0.f, a3 = 0.f;
    #pragma unroll
    for (int i = 0; i < En / 4; ++i) {
        float4 wv = w4[i]; float4 hv = h4[i];
        a0 += wv.x * hv.x; a1 += wv.y * hv.y; a2 += wv.z * hv.z; a3 += wv.w * hv.w;
    }
    out[b * NOUTn + l] = (a0 + a1) + (a2 + a3) + bo[l];
}

extern "C" void kernel_launch(void* const* d_in, const int* in_sizes, int n_in,
                              void* d_out, int out_size, void* d_ws, size_t ws_size,
                              hipStream_t stream) {
    const float* x            = (const float*)d_in[0];
    const float* pointer_init = (const float*)d_in[1];
    const float* W_in         = (const float*)d_in[2];
    const float* b_in         = (const float*)d_in[3];
    const float* ln_w         = (const float*)d_in[4];
    const float* ln_b         = (const float*)d_in[5];
    const float* jump_dest    = (const float*)d_in[6];
    const float* Wg           = (const float*)d_in[7];
    const float* bg           = (const float*)d_in[8];
    const float* cs           = (const float*)d_in[9];
    const float* Wo           = (const float*)d_in[10];
    const float* bo           = (const float*)d_in[11];
    float* out = (float*)d_out;
    (void)d_ws; (void)ws_size;   // no workspace needed: emb staged in LDS

    (void)hipFuncSetAttribute((const void*)fused2_kernel,
                              hipFuncAttributeMaxDynamicSharedMemorySize, LDSF_BYTES);
    fused2_kernel<<<Bn, 192, LDSF_BYTES, stream>>>(
        x, pointer_init, W_in, b_in, ln_w, ln_b, jump_dest, Wg, bg, cs,
        Wo, bo, out);
}